// Round 2
// baseline (311.291 us; speedup 1.0000x reference)
//
#include <hip/hip_runtime.h>

#define SS 14
#define NUM_CLS 20
#define L_COORD 5.0f
#define L_NOOBJ 0.5f

// d_ws accumulators: [0]=cls_sum [1]=noobj_sum [2]=reg_sum [3]=contain_sum

__global__ void __launch_bounds__(256) yolo_main(
    const float* __restrict__ pred,
    const float* __restrict__ tbox,
    const float* __restrict__ tcls,
    const int* __restrict__ mask,
    float* __restrict__ acc,
    int ncells) {
  int cell = blockIdx.x * blockDim.x + threadIdx.x;
  float cls_c = 0.f, noobj_c = 0.f, reg_c = 0.f, con_c = 0.f;
  if (cell < ncells) {
    const float* p = pred + (size_t)cell * 30;
    float pv[30];
#pragma unroll
    for (int i = 0; i < 15; ++i) {
      float2 v = *(const float2*)(p + 2 * i);
      pv[2 * i] = v.x;
      pv[2 * i + 1] = v.y;
    }
    float4 tb = *(const float4*)(tbox + (size_t)cell * 4);
    const float* c = tcls + (size_t)cell * 20;
    float tc[20];
#pragma unroll
    for (int i = 0; i < 5; ++i) {
      float4 v = *(const float4*)(c + 4 * i);
      tc[4 * i] = v.x;
      tc[4 * i + 1] = v.y;
      tc[4 * i + 2] = v.z;
      tc[4 * i + 3] = v.w;
    }
    float m = mask[cell] ? 1.0f : 0.0f;

    // class loss partial
    float s = 0.f;
#pragma unroll
    for (int k = 0; k < NUM_CLS; ++k) {
      float d = pv[10 + k] - tc[k];
      s += d * d;
    }
    cls_c = s * m;

    // no-object confidence partial (both boxes)
    noobj_c = (1.0f - m) * (pv[4] * pv[4] + pv[9] * pv[9]);

    // IoU for both boxes vs target (follow reference op order)
    const float invS = 1.0f / (float)SS;
    float gx0 = tb.x * invS - 0.5f * tb.z, gy0 = tb.y * invS - 0.5f * tb.w;
    float gx1 = tb.x * invS + 0.5f * tb.z, gy1 = tb.y * invS + 0.5f * tb.w;
    float ag = (gx1 - gx0) * (gy1 - gy0);

    float iou0, iou1;
    {
      float x = pv[0], y = pv[1], w = pv[2], h = pv[3];
      float px0 = x * invS - 0.5f * w, py0 = y * invS - 0.5f * h;
      float px1 = x * invS + 0.5f * w, py1 = y * invS + 0.5f * h;
      float lx = fmaxf(px0, gx0), ly = fmaxf(py0, gy0);
      float rx = fminf(px1, gx1), ry = fminf(py1, gy1);
      float iw = fmaxf(rx - lx, 0.f), ih = fmaxf(ry - ly, 0.f);
      float inter = iw * ih;
      float ap = (px1 - px0) * (py1 - py0);
      iou0 = inter / (ap + ag - inter);
    }
    {
      float x = pv[5], y = pv[6], w = pv[7], h = pv[8];
      float px0 = x * invS - 0.5f * w, py0 = y * invS - 0.5f * h;
      float px1 = x * invS + 0.5f * w, py1 = y * invS + 0.5f * h;
      float lx = fmaxf(px0, gx0), ly = fmaxf(py0, gy0);
      float rx = fminf(px1, gx1), ry = fminf(py1, gy1);
      float iw = fmaxf(rx - lx, 0.f), ih = fmaxf(ry - ly, 0.f);
      float inter = iw * ih;
      float ap = (px1 - px0) * (py1 - py0);
      iou1 = inter / (ap + ag - inter);
    }
    bool pick1 = (iou1 > iou0);  // argmax: first max wins on tie
    float bx = pick1 ? pv[5] : pv[0];
    float by = pick1 ? pv[6] : pv[1];
    float bw = pick1 ? pv[7] : pv[2];
    float bh = pick1 ? pv[8] : pv[3];
    float bc = pick1 ? pv[9] : pv[4];

    float dx = bx - tb.x, dy = by - tb.y;
    float dw = sqrtf(bw) - sqrtf(tb.z);
    float dh = sqrtf(bh) - sqrtf(tb.w);
    reg_c = m * (dx * dx + dy * dy + dw * dw + dh * dh);
    float dc = bc - 1.0f;
    con_c = m * dc * dc;
  }

  // wave reduction (64 lanes)
  float vx = cls_c, vy = noobj_c, vz = reg_c, vw = con_c;
  for (int off = 32; off >= 1; off >>= 1) {
    vx += __shfl_down(vx, off);
    vy += __shfl_down(vy, off);
    vz += __shfl_down(vz, off);
    vw += __shfl_down(vw, off);
  }
  __shared__ float4 red[4];
  int wid = threadIdx.x >> 6;
  int lane = threadIdx.x & 63;
  if (lane == 0) red[wid] = make_float4(vx, vy, vz, vw);
  __syncthreads();
  if (threadIdx.x == 0) {
    float4 t = red[0];
    for (int i = 1; i < 4; ++i) {
      t.x += red[i].x;
      t.y += red[i].y;
      t.z += red[i].z;
      t.w += red[i].w;
    }
    atomicAdd(&acc[0], t.x);
    atomicAdd(&acc[1], t.y);
    atomicAdd(&acc[2], t.z);
    atomicAdd(&acc[3], t.w);
  }
}

__global__ void yolo_final(const float* __restrict__ acc, float* __restrict__ out, float Nf) {
  if (threadIdx.x == 0 && blockIdx.x == 0) {
    float cls = acc[0] / Nf;
    float noobj = L_NOOBJ * acc[1] / Nf;
    float reg = L_COORD * acc[2] / Nf;
    float con = acc[3] / Nf;
    out[0] = reg + con + noobj + cls;  // total
    out[1] = reg;
    out[2] = con;
    out[3] = noobj;
    out[4] = cls;
  }
}

extern "C" void kernel_launch(void* const* d_in, const int* in_sizes, int n_in,
                              void* d_out, int out_size, void* d_ws, size_t ws_size,
                              hipStream_t stream) {
  const float* pred = (const float*)d_in[0];
  const float* tbox = (const float*)d_in[1];
  const float* tcls = (const float*)d_in[2];
  const int* mask = (const int*)d_in[3];
  float* out = (float*)d_out;
  float* acc = (float*)d_ws;

  int ncells = in_sizes[3];            // N*S*S
  float Nf = (float)(ncells / (SS * SS));

  hipMemsetAsync(acc, 0, 4 * sizeof(float), stream);
  int threads = 256;
  int blocks = (ncells + threads - 1) / threads;
  yolo_main<<<blocks, threads, 0, stream>>>(pred, tbox, tcls, mask, acc, ncells);
  yolo_final<<<1, 64, 0, stream>>>(acc, out, Nf);
}